// Round 6
// baseline (96.109 us; speedup 1.0000x reference)
//
#include <hip/hip_runtime.h>
#include <hip/hip_bf16.h>

#define NL  128   // layers (n)
#define DK  256   // d_in (k)
#define DO_ 256   // d_out (o)
#define MB  1024  // batch (m)

typedef __attribute__((ext_vector_type(4))) float f32x4;
typedef __attribute__((ext_vector_type(8))) short bf16x8;
typedef __attribute__((ext_vector_type(8))) unsigned short u16x8;
typedef __attribute__((ext_vector_type(4))) unsigned short u16x4;

static __device__ __forceinline__ unsigned short f2bf(float f) {
  __hip_bfloat16 h = __float2bfloat16(f);
  return __builtin_bit_cast(unsigned short, h);
}

// ---------------------------------------------------------------------------
// Prep: W[n][k][o] fp32 -> Wt in MFMA B-fragment order, bf16 (verified R4/R5):
//   unit (o, kc[8-k chunk]) -> ob=o>>4, lrow=o&15, s=kc>>2, lhi=kc&3
//   elem offset = ((n*16+ob)*8 + s)*512 + (lhi*16+lrow)*8 + (k&7)
// so a wave's B-load for (ob, s) is ONE contiguous 1KB dwordx4 per lane.
// ---------------------------------------------------------------------------
__global__ __launch_bounds__(256) void wt_prep(const float* __restrict__ W,
                                               unsigned short* __restrict__ Wt) {
  const int n     = blockIdx.y;
  const int ktile = (blockIdx.x >> 2) * 64;
  const int otile = (blockIdx.x & 3) * 64;
  __shared__ float tile[64][65];  // +1 pad: conflict-free column reads
  const float* Wn = W + (size_t)n * DK * DO_;
  const int t  = threadIdx.x;
  const int lr = t >> 4;
  const int lc = (t & 15) * 4;
#pragma unroll
  for (int p = 0; p < 4; ++p) {
    const int k = p * 16 + lr;
    const float4 v = *(const float4*)(Wn + (size_t)(ktile + k) * DO_ + otile + lc);
    tile[k][lc + 0] = v.x; tile[k][lc + 1] = v.y;
    tile[k][lc + 2] = v.z; tile[k][lc + 3] = v.w;
  }
  __syncthreads();
  const int ol = t >> 2;            // local o 0..63
  const int o  = otile + ol;
  const int kq = t & 3;
  unsigned short* Wt_n = Wt + (size_t)n * DO_ * DK;
#pragma unroll
  for (int h = 0; h < 2; ++h) {
    u16x8 w;
#pragma unroll
    for (int j = 0; j < 8; ++j) w[j] = f2bf(tile[kq * 16 + h * 8 + j][ol]);
    const int kc = (ktile >> 3) + kq * 2 + h;   // global 8-k chunk id (0..31)
    const int ob = o >> 4, lrw = o & 15, s = kc >> 2, lh = kc & 3;
    *(u16x8*)(Wt_n + ((size_t)(ob * 8 + s) * 64 + lh * 16 + lrw) * 8) = w;
  }
}

// ---------------------------------------------------------------------------
// Main: WAVE-AUTONOMOUS, ZERO BARRIERS. Each wave owns 16 m-rows x 256 o of
// one layer n: loads its 16 x-rows (1KB coalesced each), converts, writes its
// PRIVATE 8KB LDS region (lgkmcnt ordering only — no __syncthreads anywhere),
// then loops 4 o-chunks x 8 k-slices of {1 LDS A-read, 4 coalesced B-loads
// from L2-resident prefrag Wt, 4 swapped MFMA}. float4 bias + float4 stores.
// XCD swizzle: bid&7 -> n in [xcd*16,+16): 2MB Wt slice per XCD L2.
// ---------------------------------------------------------------------------
__global__ __launch_bounds__(256, 5) void nlinear_mfma(
    const float* __restrict__ X, const unsigned short* __restrict__ Wt,
    const float* __restrict__ bias, float* __restrict__ out) {
  const int wid  = blockIdx.x;
  const int n    = (wid & 7) * 16 + ((wid >> 3) & 15);
  const int mtg  = wid >> 7;          // 0..15, 64 rows per block
  const int t    = threadIdx.x;
  const int wave = t >> 6;
  const int lane = t & 63;
  const int lrow = lane & 15;
  const int lhi  = lane >> 4;
  const int mbase = mtg * 64 + wave * 16;   // wave's private 16 rows

  __shared__ unsigned short Alds[4][16 * 256];  // 8 KB per wave, private

  // ---- per-wave stage: 16 coalesced 1KB row loads, lane takes k=lane*4 ----
  const float* xw = X + ((size_t)mbase * NL + n) * DK + lane * 4;
  f32x4 xv[16];
#pragma unroll
  for (int j = 0; j < 16; ++j)
    xv[j] = *(const f32x4*)(xw + (size_t)j * NL * DK);

  char* ab = (char*)Alds[wave];
#pragma unroll
  for (int j = 0; j < 16; ++j) {
    u16x4 h;
#pragma unroll
    for (int e = 0; e < 4; ++e) h[e] = f2bf(xv[j][e]);
    // row j: chunk c = lane>>1, slot = c ^ (j&7), sub = (lane&1)*8  (R5-verified)
    *(u16x4*)(ab + j * 512 + (((lane >> 1) ^ (j & 7)) << 4) + (lane & 1) * 8) = h;
  }
  // NO barrier: private region, lgkmcnt orders write->read within the wave.

  const unsigned short* Wn = Wt + (size_t)n * DO_ * DK;
  const float* bb = bias + n * DO_ + lhi * 4;

#pragma unroll
  for (int ob = 0; ob < 4; ++ob) {   // 64-o chunk
    f32x4 acc[4];
#pragma unroll
    for (int oj = 0; oj < 4; ++oj) acc[oj] = (f32x4){0.f, 0.f, 0.f, 0.f};
#pragma unroll
    for (int s = 0; s < 8; ++s) {
      // A-fragment: row = lrow, swizzled slot (R5-verified read path)
      const bf16x8 af = *(const bf16x8*)(
          ab + lrow * 512 + (((s * 4 + lhi) ^ (lrow & 7)) << 4));
      bf16x8 bfr[4];
#pragma unroll
      for (int oj = 0; oj < 4; ++oj)  // wave-contiguous 1KB load (prefragmented)
        bfr[oj] = *(const bf16x8*)(
            Wn + ((size_t)((ob * 4 + oj) * 8 + s) * 64 + lane) * 8);
#pragma unroll
      for (int oj = 0; oj < 4; ++oj)  // SWAPPED: D[o][m], lane regs = 4 contig o
        acc[oj] = __builtin_amdgcn_mfma_f32_16x16x32_bf16(
            bfr[oj], af, acc[oj], 0, 0, 0);
    }
    // epilogue: m = mbase + lrow, o = ob*64 + oj*16 + lhi*4 + r -> float4
    const int m = mbase + lrow;
    float* orow = out + ((size_t)m * NL + n) * DO_ + ob * 64 + lhi * 4;
#pragma unroll
    for (int oj = 0; oj < 4; ++oj) {
      const f32x4 bv = *(const f32x4*)(bb + ob * 64 + oj * 16);
      *(f32x4*)(orow + oj * 16) = acc[oj] + bv;
    }
  }
}

// ---------------------------------------------------------------------------
// Fallback (only if ws too small for Wt): plain fp32, correct but slow.
// ---------------------------------------------------------------------------
__global__ __launch_bounds__(256) void nlinear_naive(
    const float* __restrict__ X, const float* __restrict__ W,
    const float* __restrict__ B, float* __restrict__ out) {
  const int n = blockIdx.y;
  const int m = blockIdx.x;
  const int o = threadIdx.x;
  __shared__ float xs[DK];
  xs[o] = X[((size_t)m * NL + n) * DK + o];
  __syncthreads();
  const float* Wn = W + (size_t)n * DK * DO_;
  float s = B[n * DO_ + o];
  for (int k = 0; k < DK; ++k) s = fmaf(xs[k], Wn[(size_t)k * DO_ + o], s);
  out[((size_t)m * NL + n) * DO_ + o] = s;
}

extern "C" void kernel_launch(void* const* d_in, const int* in_sizes, int n_in,
                              void* d_out, int out_size, void* d_ws, size_t ws_size,
                              hipStream_t stream) {
  const float* x = (const float*)d_in[0];
  const float* w = (const float*)d_in[1];
  const float* b = (const float*)d_in[2];
  float* out     = (float*)d_out;
  const size_t wt_bytes = (size_t)NL * DK * DO_ * sizeof(unsigned short);
  if (ws_size >= wt_bytes) {
    unsigned short* wt = (unsigned short*)d_ws;
    wt_prep<<<dim3(16, NL), 256, 0, stream>>>(w, wt);
    nlinear_mfma<<<dim3(2048), 256, 0, stream>>>(x, wt, b, out);
  } else {
    nlinear_naive<<<dim3(MB, NL), 256, 0, stream>>>(x, w, b, out);
  }
}

// Round 7
// 86.055 us; speedup vs baseline: 1.1168x; 1.1168x over previous
//
#include <hip/hip_runtime.h>
#include <hip/hip_bf16.h>

#define NL  128   // layers (n)
#define DK  256   // d_in (k)
#define DO_ 256   // d_out (o)
#define MB  1024  // batch (m)

typedef __attribute__((ext_vector_type(4))) float f32x4;
typedef __attribute__((ext_vector_type(8))) short bf16x8;
typedef __attribute__((ext_vector_type(8))) unsigned short u16x8;
typedef __attribute__((ext_vector_type(4))) unsigned short u16x4;

static __device__ __forceinline__ unsigned short f2bf(float f) {
  __hip_bfloat16 h = __float2bfloat16(f);
  return __builtin_bit_cast(unsigned short, h);
}

// ---------------------------------------------------------------------------
// Prep: W[n][k][o] fp32 -> Wt in MFMA B-fragment order, bf16 (verified R4/R5):
//   unit (o, kc[8-k chunk]) -> ob=o>>4, lrow=o&15, s=kc>>2, lhi=kc&3
//   elem offset = ((n*16+ob)*8 + s)*512 + (lhi*16+lrow)*8 + (k&7)
// so a wave's B-load for (ob, s) is ONE contiguous 1KB dwordx4 per lane.
// ---------------------------------------------------------------------------
__global__ __launch_bounds__(256) void wt_prep(const float* __restrict__ W,
                                               unsigned short* __restrict__ Wt) {
  const int n     = blockIdx.y;
  const int ktile = (blockIdx.x >> 2) * 64;
  const int otile = (blockIdx.x & 3) * 64;
  __shared__ float tile[64][65];  // +1 pad: conflict-free column reads
  const float* Wn = W + (size_t)n * DK * DO_;
  const int t  = threadIdx.x;
  const int lr = t >> 4;
  const int lc = (t & 15) * 4;
#pragma unroll
  for (int p = 0; p < 4; ++p) {
    const int k = p * 16 + lr;
    const float4 v = *(const float4*)(Wn + (size_t)(ktile + k) * DO_ + otile + lc);
    tile[k][lc + 0] = v.x; tile[k][lc + 1] = v.y;
    tile[k][lc + 2] = v.z; tile[k][lc + 3] = v.w;
  }
  __syncthreads();
  const int ol = t >> 2;            // local o 0..63
  const int o  = otile + ol;
  const int kq = t & 3;
  unsigned short* Wt_n = Wt + (size_t)n * DO_ * DK;
#pragma unroll
  for (int h = 0; h < 2; ++h) {
    u16x8 w;
#pragma unroll
    for (int j = 0; j < 8; ++j) w[j] = f2bf(tile[kq * 16 + h * 8 + j][ol]);
    const int kc = (ktile >> 3) + kq * 2 + h;   // global 8-k chunk id (0..31)
    const int ob = o >> 4, lrw = o & 15, s = kc >> 2, lh = kc & 3;
    *(u16x8*)(Wt_n + ((size_t)(ob * 8 + s) * 64 + lh * 16 + lrw) * 8) = w;
  }
}

// ---------------------------------------------------------------------------
// Main: R5 scaled 2x. Block = (n, 64-row m-tile), 512 thr = 8 waves.
// Stage: wave w stages rows w*8..w*8+8 exactly as R5 (1KB coalesced row loads,
// XOR-swizzled LDS write). ONE barrier. Compute: wave w owns
// (m-half = w>>2, o-64-slice = w&3): acc[2][4], verified swizzled A-reads,
// coalesced prefrag B-loads, swapped MFMA, float4 bias+stores.
// XCD swizzle: bid&7 -> n in [xcd*16,+16): 2MB Wt slice per XCD L2.
// ---------------------------------------------------------------------------
__global__ __launch_bounds__(512, 6) void nlinear_mfma(
    const float* __restrict__ X, const unsigned short* __restrict__ Wt,
    const float* __restrict__ bias, float* __restrict__ out) {
  const int wid  = blockIdx.x;
  const int n    = (wid & 7) * 16 + ((wid >> 3) & 15);
  const int mg   = wid >> 7;          // 0..15, 64 rows each
  const int t    = threadIdx.x;
  const int wave = t >> 6;            // 0..7
  const int lane = t & 63;
  const int lrow = lane & 15;
  const int lhi  = lane >> 4;
  const int mbase = mg * 64;

  __shared__ unsigned short Alds[64 * 256];  // 32 KB, 512B rows, swizzled slots

  // ---- stage: wave w loads rows w*8+j (j=0..7), lane takes k=lane*4 ----
  const float* xw = X + ((size_t)(mbase + wave * 8) * NL + n) * DK + lane * 4;
  f32x4 xv[8];
#pragma unroll
  for (int j = 0; j < 8; ++j)
    xv[j] = *(const f32x4*)(xw + (size_t)j * NL * DK);

  char* ab = (char*)Alds;
#pragma unroll
  for (int j = 0; j < 8; ++j) {
    u16x4 h;
#pragma unroll
    for (int e = 0; e < 4; ++e) h[e] = f2bf(xv[j][e]);
    // row = wave*8+j; chunk c = lane>>1; slot = c ^ (row&7) = c ^ j  (R5-verified)
    *(u16x4*)(ab + (wave * 8 + j) * 512 + (((lane >> 1) ^ j) << 4) + (lane & 1) * 8) = h;
  }
  __syncthreads();  // the only barrier

  const int mh = wave >> 2;   // m-half: rows mh*32 .. +32
  const int ob = wave & 3;    // o-64-slice
  const unsigned short* Wn = Wt + (size_t)n * DO_ * DK;

  f32x4 acc[2][4];
#pragma unroll
  for (int mt = 0; mt < 2; ++mt)
#pragma unroll
    for (int oj = 0; oj < 4; ++oj) acc[mt][oj] = (f32x4){0.f, 0.f, 0.f, 0.f};

#pragma unroll
  for (int s = 0; s < 8; ++s) {
    bf16x8 bfr[4], af[2];
#pragma unroll
    for (int oj = 0; oj < 4; ++oj)  // wave-contiguous 1KB load (prefragmented)
      bfr[oj] = *(const bf16x8*)(
          Wn + ((size_t)((ob * 4 + oj) * 8 + s) * 64 + lane) * 8);
#pragma unroll
    for (int mt = 0; mt < 2; ++mt) {
      const int row = mh * 32 + mt * 16 + lrow;
      af[mt] = *(const bf16x8*)(ab + row * 512 + (((s * 4 + lhi) ^ (row & 7)) << 4));
    }
#pragma unroll
    for (int oj = 0; oj < 4; ++oj)
#pragma unroll
      for (int mt = 0; mt < 2; ++mt)  // SWAPPED: D[o][m], lane regs = 4 contig o
        acc[mt][oj] = __builtin_amdgcn_mfma_f32_16x16x32_bf16(
            bfr[oj], af[mt], acc[mt][oj], 0, 0, 0);
  }

  // epilogue: m = mbase+mh*32+mt*16+lrow, o = ob*64 + oj*16 + lhi*4 + r
  const float* bb = bias + n * DO_ + ob * 64 + lhi * 4;
  f32x4 bv[4];
#pragma unroll
  for (int oj = 0; oj < 4; ++oj) bv[oj] = *(const f32x4*)(bb + oj * 16);
#pragma unroll
  for (int mt = 0; mt < 2; ++mt) {
    const int m = mbase + mh * 32 + mt * 16 + lrow;
    float* orow = out + ((size_t)m * NL + n) * DO_ + ob * 64 + lhi * 4;
#pragma unroll
    for (int oj = 0; oj < 4; ++oj)
      *(f32x4*)(orow + oj * 16) = acc[mt][oj] + bv[oj];
  }
}

// ---------------------------------------------------------------------------
// Fallback (only if ws too small for Wt): plain fp32, correct but slow.
// ---------------------------------------------------------------------------
__global__ __launch_bounds__(256) void nlinear_naive(
    const float* __restrict__ X, const float* __restrict__ W,
    const float* __restrict__ B, float* __restrict__ out) {
  const int n = blockIdx.y;
  const int m = blockIdx.x;
  const int o = threadIdx.x;
  __shared__ float xs[DK];
  xs[o] = X[((size_t)m * NL + n) * DK + o];
  __syncthreads();
  const float* Wn = W + (size_t)n * DK * DO_;
  float s = B[n * DO_ + o];
  for (int k = 0; k < DK; ++k) s = fmaf(xs[k], Wn[(size_t)k * DO_ + o], s);
  out[((size_t)m * NL + n) * DO_ + o] = s;
}

extern "C" void kernel_launch(void* const* d_in, const int* in_sizes, int n_in,
                              void* d_out, int out_size, void* d_ws, size_t ws_size,
                              hipStream_t stream) {
  const float* x = (const float*)d_in[0];
  const float* w = (const float*)d_in[1];
  const float* b = (const float*)d_in[2];
  float* out     = (float*)d_out;
  const size_t wt_bytes = (size_t)NL * DK * DO_ * sizeof(unsigned short);
  if (ws_size >= wt_bytes) {
    unsigned short* wt = (unsigned short*)d_ws;
    wt_prep<<<dim3(16, NL), 256, 0, stream>>>(w, wt);
    nlinear_mfma<<<dim3(2048), 512, 0, stream>>>(x, wt, b, out);
  } else {
    nlinear_naive<<<dim3(MB, NL), 256, 0, stream>>>(x, w, b, out);
  }
}

// Round 8
// 79.897 us; speedup vs baseline: 1.2029x; 1.0771x over previous
//
#include <hip/hip_runtime.h>
#include <hip/hip_bf16.h>

#define NL  128   // layers (n)
#define DK  256   // d_in (k)
#define DO_ 256   // d_out (o)
#define MB  1024  // batch (m)

typedef __attribute__((ext_vector_type(4))) float f32x4;
typedef __attribute__((ext_vector_type(8))) short bf16x8;
typedef __attribute__((ext_vector_type(8))) unsigned short u16x8;
typedef __attribute__((ext_vector_type(4))) unsigned short u16x4;

static __device__ __forceinline__ unsigned short f2bf(float f) {
  __hip_bfloat16 h = __float2bfloat16(f);
  return __builtin_bit_cast(unsigned short, h);
}

// ---------------------------------------------------------------------------
// Prep: W[n][k][o] fp32 -> Wt in MFMA B-fragment order, bf16 (verified R4-R7):
//   unit (o, kc[8-k chunk]) -> ob=o>>4, lrow=o&15, s=kc>>2, lhi=kc&3
//   elem offset = ((n*16+ob)*8 + s)*512 + (lhi*16+lrow)*8 + (k&7)
// so a wave's B-load for (ob, s) is ONE contiguous 1KB dwordx4 per lane.
// ---------------------------------------------------------------------------
__global__ __launch_bounds__(256) void wt_prep(const float* __restrict__ W,
                                               unsigned short* __restrict__ Wt) {
  const int n     = blockIdx.y;
  const int ktile = (blockIdx.x >> 2) * 64;
  const int otile = (blockIdx.x & 3) * 64;
  __shared__ float tile[64][65];  // +1 pad: conflict-free column reads
  const float* Wn = W + (size_t)n * DK * DO_;
  const int t  = threadIdx.x;
  const int lr = t >> 4;
  const int lc = (t & 15) * 4;
#pragma unroll
  for (int p = 0; p < 4; ++p) {
    const int k = p * 16 + lr;
    const float4 v = *(const float4*)(Wn + (size_t)(ktile + k) * DO_ + otile + lc);
    tile[k][lc + 0] = v.x; tile[k][lc + 1] = v.y;
    tile[k][lc + 2] = v.z; tile[k][lc + 3] = v.w;
  }
  __syncthreads();
  const int ol = t >> 2;            // local o 0..63
  const int o  = otile + ol;
  const int kq = t & 3;
  unsigned short* Wt_n = Wt + (size_t)n * DO_ * DK;
#pragma unroll
  for (int h = 0; h < 2; ++h) {
    u16x8 w;
#pragma unroll
    for (int j = 0; j < 8; ++j) w[j] = f2bf(tile[kq * 16 + h * 8 + j][ol]);
    const int kc = (ktile >> 3) + kq * 2 + h;   // global 8-k chunk id (0..31)
    const int ob = o >> 4, lrw = o & 15, s = kc >> 2, lh = kc & 3;
    *(u16x8*)(Wt_n + ((size_t)(ob * 8 + s) * 64 + lh * 16 + lrw) * 8) = w;
  }
}

// ---------------------------------------------------------------------------
// Main: R7 structure + ILP unlock. Block = (n, 64-row m-tile), 512 thr.
// Stage identical to R7 (1KB coalesced row loads, XOR-swizzled LDS). ONE
// barrier. Compute: wave owns a 32-o slice (ob=wave) x ALL 64 m: acc[4][2],
// NO duplicate B-reads in the block, explicit 2-deep B-prefetch pipeline
// (static-indexed, fully-unrolled s-loop). launch_bounds(512,4) -> VGPR 128:
// the compiler finally has room to keep 2 s-steps of loads in flight.
// XCD swizzle: bid&7 -> n in [xcd*16,+16): 2MB Wt slice per XCD L2.
// ---------------------------------------------------------------------------
__global__ __launch_bounds__(512, 4) void nlinear_mfma(
    const float* __restrict__ X, const unsigned short* __restrict__ Wt,
    const float* __restrict__ bias, float* __restrict__ out) {
  const int wid  = blockIdx.x;
  const int n    = (wid & 7) * 16 + ((wid >> 3) & 15);
  const int mg   = wid >> 7;          // 0..15, 64 rows each
  const int t    = threadIdx.x;
  const int wave = t >> 6;            // 0..7 = o-slice of 32
  const int lane = t & 63;
  const int lrow = lane & 15;
  const int lhi  = lane >> 4;
  const int mbase = mg * 64;

  __shared__ unsigned short Alds[64 * 256];  // 32 KB, 512B rows, swizzled slots

  // ---- stage: wave w loads rows w*8+j (j=0..7), lane takes k=lane*4 ----
  const float* xw = X + ((size_t)(mbase + wave * 8) * NL + n) * DK + lane * 4;
  f32x4 xv[8];
#pragma unroll
  for (int j = 0; j < 8; ++j)
    xv[j] = *(const f32x4*)(xw + (size_t)j * NL * DK);

  // bias: issue early, independent of everything
  const float* bb = bias + n * DO_ + wave * 32 + lhi * 4;
  f32x4 bv[2];
#pragma unroll
  for (int oj = 0; oj < 2; ++oj) bv[oj] = *(const f32x4*)(bb + oj * 16);

  char* ab = (char*)Alds;
#pragma unroll
  for (int j = 0; j < 8; ++j) {
    u16x4 h;
#pragma unroll
    for (int e = 0; e < 4; ++e) h[e] = f2bf(xv[j][e]);
    // row = wave*8+j; chunk c = lane>>1; slot = c ^ (row&7) = c ^ j  (verified)
    *(u16x4*)(ab + (wave * 8 + j) * 512 + (((lane >> 1) ^ j) << 4) + (lane & 1) * 8) = h;
  }
  __syncthreads();  // the only barrier

  const unsigned short* Wn = Wt + (size_t)n * DO_ * DK;

  f32x4 acc[4][2];
#pragma unroll
  for (int mt = 0; mt < 4; ++mt)
#pragma unroll
    for (int oj = 0; oj < 2; ++oj) acc[mt][oj] = (f32x4){0.f, 0.f, 0.f, 0.f};

  // B-load helper: coalesced 1KB per instr from prefragmented, L2-resident Wt
#define BLOAD(s, oj) \
  (*(const bf16x8*)(Wn + ((size_t)(((wave * 2 + (oj)) * 8) + (s)) * 64 + lane) * 8))

  // 2-deep explicit B prefetch pipeline (all indices compile-time: no scratch)
  bf16x8 bA0 = BLOAD(0, 0), bA1 = BLOAD(0, 1);
  bf16x8 bB0 = BLOAD(1, 0), bB1 = BLOAD(1, 1);

#pragma unroll
  for (int s = 0; s < 8; ++s) {
    const bf16x8 bc0 = (s & 1) ? bB0 : bA0;
    const bf16x8 bc1 = (s & 1) ? bB1 : bA1;
    if (s < 6) {  // refill the slot just consumed with s+2
      if (s & 1) { bB0 = BLOAD(s + 2, 0); bB1 = BLOAD(s + 2, 1); }
      else       { bA0 = BLOAD(s + 2, 0); bA1 = BLOAD(s + 2, 1); }
    }
    bf16x8 af[4];
#pragma unroll
    for (int mt = 0; mt < 4; ++mt) {
      const int row = mt * 16 + lrow;
      af[mt] = *(const bf16x8*)(ab + row * 512 + (((s * 4 + lhi) ^ (row & 7)) << 4));
    }
#pragma unroll
    for (int mt = 0; mt < 4; ++mt) {  // SWAPPED: D[o][m], lane regs = 4 contig o
      acc[mt][0] = __builtin_amdgcn_mfma_f32_16x16x32_bf16(bc0, af[mt], acc[mt][0], 0, 0, 0);
      acc[mt][1] = __builtin_amdgcn_mfma_f32_16x16x32_bf16(bc1, af[mt], acc[mt][1], 0, 0, 0);
    }
  }
#undef BLOAD

  // epilogue: m = mbase + mt*16 + lrow, o = wave*32 + oj*16 + lhi*4 + r
#pragma unroll
  for (int mt = 0; mt < 4; ++mt) {
    const int m = mbase + mt * 16 + lrow;
    float* orow = out + ((size_t)m * NL + n) * DO_ + wave * 32 + lhi * 4;
#pragma unroll
    for (int oj = 0; oj < 2; ++oj)
      *(f32x4*)(orow + oj * 16) = acc[mt][oj] + bv[oj];
  }
}

// ---------------------------------------------------------------------------
// Fallback (only if ws too small for Wt): plain fp32, correct but slow.
// ---------------------------------------------------------------------------
__global__ __launch_bounds__(256) void nlinear_naive(
    const float* __restrict__ X, const float* __restrict__ W,
    const float* __restrict__ B, float* __restrict__ out) {
  const int n = blockIdx.y;
  const int m = blockIdx.x;
  const int o = threadIdx.x;
  __shared__ float xs[DK];
  xs[o] = X[((size_t)m * NL + n) * DK + o];
  __syncthreads();
  const float* Wn = W + (size_t)n * DK * DO_;
  float s = B[n * DO_ + o];
  for (int k = 0; k < DK; ++k) s = fmaf(xs[k], Wn[(size_t)k * DO_ + o], s);
  out[((size_t)m * NL + n) * DO_ + o] = s;
}

extern "C" void kernel_launch(void* const* d_in, const int* in_sizes, int n_in,
                              void* d_out, int out_size, void* d_ws, size_t ws_size,
                              hipStream_t stream) {
  const float* x = (const float*)d_in[0];
  const float* w = (const float*)d_in[1];
  const float* b = (const float*)d_in[2];
  float* out     = (float*)d_out;
  const size_t wt_bytes = (size_t)NL * DK * DO_ * sizeof(unsigned short);
  if (ws_size >= wt_bytes) {
    unsigned short* wt = (unsigned short*)d_ws;
    wt_prep<<<dim3(16, NL), 256, 0, stream>>>(w, wt);
    nlinear_mfma<<<dim3(2048), 512, 0, stream>>>(x, wt, b, out);
  } else {
    nlinear_naive<<<dim3(MB, NL), 256, 0, stream>>>(x, w, b, out);
  }
}